// Round 11
// baseline (185.315 us; speedup 1.0000x reference)
//
#include <hip/hip_runtime.h>
#include <hip/hip_bf16.h>
#include <string.h>

// DeformableConv2d: B=4, C=256, O=256, H=W=64, K=3, pad=1, stride=1
// Round 11: K3 split into 512 half-row blocks (32 px) -> 2 blocks/CU,
// 4 waves/SIMD, half per-lane gather state (32 loads/lane/tap), 16-reg acc.
// LDS padded to ~68KB so exactly 2 blocks/CU co-reside (compiler then budgets
// 128 VGPRs -> stays in the clean no-spill regime seen in r10).
// Per-acc K-order identical to r10 -> absmax must stay 0.015625.
// K1, K2 byte-identical to round 10 (= round 9).
// Workspace: ws_off 1769472 B | ws_b 1179648 B | ws_a2 147456 B = 3096576 B.

typedef __attribute__((ext_vector_type(8))) short short8;
typedef __attribute__((ext_vector_type(8))) _Float16 half8;
typedef __attribute__((ext_vector_type(16))) float floatx16;

__device__ __forceinline__ unsigned bfbits(float f) {
    unsigned u;
    __builtin_memcpy(&u, &f, 4);
    return (u + 0x7fffu + ((u >> 16) & 1u)) >> 16;   // RNE f32->bf16
}
__device__ __forceinline__ unsigned pack_bf16(float lo, float hi) {
    return bfbits(lo) | (bfbits(hi) << 16);
}
__device__ __forceinline__ unsigned pack_f16(float lo, float hi) {
    _Float16 a = (_Float16)lo, b = (_Float16)hi;
    unsigned short ua, ub;
    __builtin_memcpy(&ua, &a, 2);
    __builtin_memcpy(&ub, &b, 2);
    return (unsigned)ua | ((unsigned)ub << 16);
}

// async global->LDS DMA, 4 B per lane; lane l's data lands at lds + l*4
__device__ __forceinline__ void gl_lds4(const float* g, float* l) {
    __builtin_amdgcn_global_load_lds(
        (const __attribute__((address_space(1))) unsigned int*)g,
        (__attribute__((address_space(3))) unsigned int*)l,
        4, 0, 0);
}

// ---------------------------------------------------------------------------
// K1: weight pack (verbatim rounds 4-10).
// ---------------------------------------------------------------------------
__global__ __launch_bounds__(256) void weight_pack_kernel(
    const float* __restrict__ w, const float* __restrict__ off_w,
    const float* __restrict__ mask_w,
    unsigned short* __restrict__ ws_b, unsigned short* __restrict__ ws_a2)
{
    __shared__ float slab[32 * 289];
    const int bid = blockIdx.x;
    const int tid = threadIdx.x;

    if (bid < 64) {
        const int nt = bid >> 3, cb = bid & 7;
        const float* wbase = w + (size_t)nt * 32 * 2304 + cb * 288;
#pragma unroll
        for (int i = 0; i < 9; ++i) {
            int idx = i * 256 + tid;               // 0..2303
            int o = idx / 72, f4 = idx % 72;
            float4 v = *(const float4*)&wbase[(size_t)o * 2304 + f4 * 4];
            slab[o * 289 + f4 * 4 + 0] = v.x;
            slab[o * 289 + f4 * 4 + 1] = v.y;
            slab[o * 289 + f4 * 4 + 2] = v.z;
            slab[o * 289 + f4 * 4 + 3] = v.w;
        }
        __syncthreads();
#pragma unroll
        for (int pass = 0; pass < 5; ++pass) {
            int rid = pass * 8 + (tid >> 5);
            if (rid < 36) {
                int kk = rid >> 2, q = rid & 3;
                int no = tid & 31;
                unsigned pk[4];
#pragma unroll
                for (int i = 0; i < 4; ++i) {
                    float f0 = slab[no * 289 + (q * 8 + 2 * i) * 9 + kk];
                    float f1 = slab[no * 289 + (q * 8 + 2 * i + 1) * 9 + kk];
                    pk[i] = pack_bf16(f0, f1);
                }
                size_t u = ((size_t)nt * 288 + kk * 32 + cb * 4 + q) * 32 + no;
                *(uint4*)&ws_b[u * 8] = make_uint4(pk[0], pk[1], pk[2], pk[3]);
            }
        }
    } else {
        int e = (bid - 64) * 256 + tid;       // 0..9215
        int lan = e & 31;                     // oc row
        int ku = e >> 5;                      // 0..287
        int kk = ku >> 5;
        int c0 = (ku & 31) * 8;
        int o = lan;
        float f[8];
#pragma unroll
        for (int j = 0; j < 8; ++j) {
            int c = c0 + j;
            float v = 0.f;
            if (o < 18)      v = off_w[((size_t)o * 256 + c) * 9 + kk];
            else if (o < 27) v = mask_w[((size_t)(o - 18) * 256 + c) * 9 + kk];
            f[j] = v;
        }
        unsigned pk[4];
#pragma unroll
        for (int i = 0; i < 4; ++i) pk[i] = pack_f16(f[2 * i], f[2 * i + 1]);
        *(uint4*)&ws_a2[(size_t)e * 8] = make_uint4(pk[0], pk[1], pk[2], pk[3]);
    }
}

// ---------------------------------------------------------------------------
// K2: offset/mask conv via f16 MFMA with global_load_lds staging
// (verbatim rounds 9/10).
// ---------------------------------------------------------------------------
__global__ __launch_bounds__(512) void offmask_mfma_kernel(
    const float* __restrict__ x, const unsigned short* __restrict__ ws_a2,
    const float* __restrict__ off_b, const float* __restrict__ mask_b,
    float* __restrict__ ws_off)
{
    __shared__ float stage[256 * 64];     // 64 KiB: x[.][hh][.] for one row
    __shared__ uint4 bufB[2][2048];       // 64 KiB; aliased as red[] in epilogue
    const int bid = blockIdx.x;
    const int row = (bid & 7) * 32 + (bid >> 3);
    const int b = row >> 6, ho = row & 63;
    const int tid = threadIdx.x;
    const int l = tid & 63;
    const int w = tid >> 6;
    const int lan = l & 31, h = l >> 5;
    const float* xb = x + (size_t)b * 256 * 4096;

    floatx16 acc;
#pragma unroll
    for (int r = 0; r < 16; ++r) acc[r] = 0.f;

    const int n = l;                 // pixel within row
    const int ku0 = w;               // 0..7
    const int ntile = w >> 2, kq = w & 3;

    auto stage_row = [&](int hh) {
        if (hh >= 0 && hh < 64) {
            const float* src = xb + hh * 64;
#pragma unroll
            for (int i = 0; i < 32; ++i) {
                int c = w * 32 + i;                 // wave-uniform channel
                gl_lds4(src + (size_t)c * 4096 + l, &stage[c * 64]);
            }
        } else {
#pragma unroll
            for (int i = 0; i < 32; ++i) {
                int c = w * 32 + i;
                stage[c * 64 + l] = 0.f;
            }
        }
    };

    auto build = [&](int kk, int kx) {
        int px = n - 1 + kx;
        bool vx = (px >= 0 && px < 64);
        int pxc = vx ? px : 0;
        int buf = kk & 1;
#pragma unroll
        for (int j = 0; j < 4; ++j) {
            int ku = ku0 + 8 * j;
            int c0 = ku * 8;
            float v[8];
#pragma unroll
            for (int jj = 0; jj < 8; ++jj) {
                float t = stage[(c0 + jj) * 64 + pxc];
                v[jj] = vx ? t : 0.f;
            }
            unsigned pk[4];
#pragma unroll
            for (int i = 0; i < 4; ++i) pk[i] = pack_f16(v[2 * i], v[2 * i + 1]);
            bufB[buf][ku * 64 + n] = make_uint4(pk[0], pk[1], pk[2], pk[3]);
        }
    };

    auto domfma = [&](int kk) {
        int buf = kk & 1;
        const uint4* a4 = (const uint4*)ws_a2;
#pragma unroll
        for (int s4 = 0; s4 < 4; ++s4) {
            int s = kq * 4 + s4;         // K-step 0..15 within chunk
            int kul = s * 2 + h;         // local ku 0..31
            uint4 ua = a4[(size_t)(kk * 32 + kul) * 32 + lan];
            uint4 ub = bufB[buf][kul * 64 + ntile * 32 + lan];
            half8 a, bb;
            __builtin_memcpy(&a, &ua, 16);
            __builtin_memcpy(&bb, &ub, 16);
            acc = __builtin_amdgcn_mfma_f32_32x32x16_f16(a, bb, acc, 0, 0, 0);
        }
    };

    for (int ky = 0; ky < 3; ++ky) {
        __syncthreads();                 // prior builds done reading stage
        stage_row(ho - 1 + ky);
        __syncthreads();                 // DMA drained (vmcnt(0) before barrier)
#pragma unroll
        for (int kx = 0; kx < 3; ++kx) {
            int kk = ky * 3 + kx;
            build(kk, kx);
            __syncthreads();
            domfma(kk);
        }
    }
    __syncthreads();                     // last domfma done before red alias

    // cross-wave partial-C reduction (4 K-quarters per n-tile) - verbatim
    float* red = (float*)bufB;           // 8 waves x 64 lanes x 16 = 32 KiB
#pragma unroll
    for (int r = 0; r < 16; ++r) red[(w * 64 + l) * 16 + r] = acc[r];
    __syncthreads();
    for (int idx = tid; idx < 27 * 64; idx += 512) {
        int oc = idx >> 6, wo = idx & 63;
        int nt2 = wo >> 5, nn = wo & 31;
        int h2 = (oc >> 2) & 1;
        int r = (oc & 3) | ((oc >> 3) << 2);
        int lane2 = nn + 32 * h2;
        float s = 0.f;
#pragma unroll
        for (int kq2 = 0; kq2 < 4; ++kq2)
            s += red[((nt2 * 4 + kq2) * 64 + lane2) * 16 + r];
        float v;
        if (oc < 18) {
            v = s + off_b[oc];
        } else {
            float t = s + mask_b[oc - 18];
            v = 1.f / (1.f + expf(-t));
        }
        ws_off[(size_t)row * 1728 + idx] = v;
    }
}

// ---------------------------------------------------------------------------
// K3: fused deformable sampling + GEMM, half-row blocks.
// 512 blocks: bid&7 = XCD, row = (bid&7)*32 + (bid>>4), half s = (bid>>3)&1,
// pixel base n0 = s*32.  8 waves; wave wid samples unit wid (32 ch; lane:
// pixel p = l&31, channel-half = l>>5 -> 32 loads/lane/tap) and owns m-tile
// wid (16 acc regs, 1 n-tile).  One barrier per tap.
// ---------------------------------------------------------------------------
__global__ __launch_bounds__(512) void deform_gemm_kernel(
    const float* __restrict__ x, const float* __restrict__ ws_off,
    const unsigned short* __restrict__ ws_b, const float* __restrict__ bias,
    float* __restrict__ out)
{
    __shared__ float offs[896];        // [ch(27)][p(32)], padded
    __shared__ float biasl[256];
    __shared__ uint4 tile[2][2048];    // [buf][ku(32)*32 + p]; padded to 2x32KB
                                       // (total ~68KB -> exactly 2 blocks/CU)

    const int bid = blockIdx.x;
    const int row = (bid & 7) * 32 + (bid >> 4);
    const int s = (bid >> 3) & 1;
    const int n0 = s * 32;
    const int b = row >> 6, ho = row & 63;
    const int tid = threadIdx.x;
    const int l = tid & 63;
    const int wid = tid >> 6;          // 0..7
    const int lan = l & 31, h = l >> 5;

    for (int i = tid; i < 864; i += 512)
        offs[i] = ws_off[(size_t)row * 1728 + (i >> 5) * 64 + n0 + (i & 31)];
    if (tid < 256) biasl[tid] = bias[tid];
    __syncthreads();

    const float* xb = x + (size_t)b * 256 * 4096;
    const uint4* wb4 = (const uint4*)ws_b;

    // per-tap state (per lane, pixel p): premultiplied weights + row offsets
    float a00 = 0.f, a01 = 0.f, a10 = 0.f, a11 = 0.f;
    int e0 = 0, e1 = 0;

    floatx16 acc;
#pragma unroll
    for (int r = 0; r < 16; ++r) acc[r] = 0.f;

    const int p = l & 31;              // pixel within half-row
    const int chh = l >> 5;            // channel-half selector

    auto compute_tap = [&](int kk) {
        int ky = kk / 3, kx = kk - ky * 3;
        float dy = offs[(2 * kk) * 32 + p];
        float dx = offs[(2 * kk + 1) * 32 + p];
        float mk = offs[(18 + kk) * 32 + p];
        float py = (float)(ho - 1 + ky) + dy;
        float px = (float)(n0 + p - 1 + kx) + dx;
        float y0f = floorf(py), x0f = floorf(px);
        float wy1 = py - y0f, wx1 = px - x0f;
        float wy0 = 1.f - wy1, wx0 = 1.f - wx1;
        int y0 = (int)y0f, xi0 = (int)x0f;
        int y1 = y0 + 1;
        float vy0 = (y0 >= 0 && y0 < 64) ? 1.f : 0.f;
        float vy1 = (y1 >= 0 && y1 < 64) ? 1.f : 0.f;
        float vx0 = (xi0 >= 0 && xi0 < 64) ? 1.f : 0.f;
        float vx1 = (xi0 >= -1 && xi0 < 63) ? 1.f : 0.f;   // validity of xi0+1
        float wxa, wxb;
        if (xi0 < 0)        { wxa = wx1 * vx1; wxb = 0.f; }        // corner1 at v.x
        else if (xi0 >= 63) { wxa = 0.f;       wxb = wx0 * vx0; }  // corner0 at v.y
        else                { wxa = wx0;       wxb = wx1; }        // both valid
        float wr0 = wy0 * vy0 * mk, wr1 = wy1 * vy1 * mk;
        a00 = wr0 * wxa; a01 = wr0 * wxb;
        a10 = wr1 * wxa; a11 = wr1 * wxb;
        int yc0 = min(max(y0, 0), 63), yc1 = min(max(y1, 0), 63);
        int bx = min(max(xi0, 0), 62);
        e0 = yc0 * 64 + bx;
        e1 = yc1 * 64 + bx;
    };

    auto sample_unit = [&](int buf) {
#pragma unroll
        for (int u2 = 0; u2 < 2; ++u2) {
            const int u = chh * 2 + u2;                 // 8-channel group 0..3
            const float* bp = xb + (size_t)(wid * 32 + u * 8) * 4096;
            unsigned pk[4];
#pragma unroll
            for (int j = 0; j < 4; ++j) {
                const float* q0 = bp + (size_t)(2 * j) * 4096;
                const float* q1 = q0 + 4096;
                float2 r0a, r0b, r1a, r1b;
                __builtin_memcpy(&r0a, q0 + e0, 8);
                __builtin_memcpy(&r0b, q0 + e1, 8);
                __builtin_memcpy(&r1a, q1 + e0, 8);
                __builtin_memcpy(&r1b, q1 + e1, 8);
                float v0 = a00 * r0a.x + a01 * r0a.y + a10 * r0b.x + a11 * r0b.y;
                float v1 = a00 * r1a.x + a01 * r1a.y + a10 * r1b.x + a11 * r1b.y;
                pk[j] = pack_bf16(v0, v1);
            }
            tile[buf][(wid * 4 + u) * 32 + p] = make_uint4(pk[0], pk[1], pk[2], pk[3]);
        }
    };

    auto do_mfma = [&](int kk, int buf) {
#pragma unroll
        for (int ks = 0; ks < 16; ++ks) {
            int kul = ks * 2 + h;          // local ku 0..31
            uint4 ua = wb4[((size_t)wid * 288 + kk * 32 + kul) * 32 + lan];
            uint4 ub = tile[buf][kul * 32 + lan];
            short8 a, bb;
            __builtin_memcpy(&a, &ua, 16);
            __builtin_memcpy(&bb, &ub, 16);
            acc = __builtin_amdgcn_mfma_f32_32x32x16_bf16(a, bb, acc, 0, 0, 0);
        }
    };

    compute_tap(0);
    sample_unit(0);
    __syncthreads();

    for (int kk = 0; kk < 9; ++kk) {
        if (kk + 1 < 9) {
            compute_tap(kk + 1);
            sample_unit((kk + 1) & 1);
        }
        do_mfma(kk, kk & 1);
        __syncthreads();
    }

    // epilogue: wave wid owns m-tile wid; columns n0..n0+31
#pragma unroll
    for (int r = 0; r < 16; ++r) {
        int o = wid * 32 + (r & 3) + 8 * (r >> 2) + 4 * h;
        int woo = n0 + lan;
        out[(((size_t)b * 256 + o) * 64 + ho) * 64 + woo] = acc[r] + biasl[o];
    }
}

extern "C" void kernel_launch(void* const* d_in, const int* in_sizes, int n_in,
                              void* d_out, int out_size, void* d_ws, size_t ws_size,
                              hipStream_t stream) {
    const float* x      = (const float*)d_in[0];
    const float* weight = (const float*)d_in[1];
    const float* bias   = (const float*)d_in[2];
    const float* off_w  = (const float*)d_in[3];
    const float* off_b  = (const float*)d_in[4];
    const float* mask_w = (const float*)d_in[5];
    const float* mask_b = (const float*)d_in[6];
    float* out = (float*)d_out;

    float* ws_off = (float*)d_ws;                                      // 1,769,472 B
    unsigned short* ws_b  = (unsigned short*)((char*)d_ws + 1769472);  // 1,179,648 B
    unsigned short* ws_a2 = (unsigned short*)((char*)d_ws + 2949120);  //   147,456 B

    hipLaunchKernelGGL(weight_pack_kernel, dim3(100), dim3(256), 0, stream,
                       weight, off_w, mask_w, ws_b, ws_a2);
    hipLaunchKernelGGL(offmask_mfma_kernel, dim3(256), dim3(512), 0, stream,
                       x, ws_a2, off_b, mask_b, ws_off);
    hipLaunchKernelGGL(deform_gemm_kernel, dim3(512), dim3(512), 0, stream,
                       x, ws_off, ws_b, bias, out);
}